// Round 6
// baseline (157.886 us; speedup 1.0000x reference)
//
#include <hip/hip_runtime.h>

// ---------------------------------------------------------------------------
// UniversalBlockEncoder: algebraically folded attention pooling.
//
//   u_i = silu(W1 x_i + b1)                 (the only per-point nonlinearity)
//   s_h(i) = g_h . u_i + d_h    with g_h = W2^T (scale Wk_h^T q_h)
//   p = exp(s)  (scores O(3), f32-safe without max-subtraction)
//   T_h = sum_i p_h(i) u_i ,  l_h = sum_i p_h(i)
//   out = Wo ( Wv ( W2 (T/l) + b2 ) + bv ) + bo
//
// R6: R5 structure, but phase 2 (T accumulation) moved to the MFMA pipe:
//     u staged bf16 [j][pt] stride 72 (16B-aligned rows, 2-way writes=free),
//     p staged bf16 [h][pt]; T += U(j,pt) x P(pt,h) via 8x mfma 16x16x32
//     per group (M=j-tiles, N=h, K=pt). Kills the 64 ds_read_b128 p4s
//     broadcasts + 320 fma insts per group that made the LDS pipe ~73% busy.
// ---------------------------------------------------------------------------

#define LOG2E 1.44269504088896340736f
#define NLN2  (-0.69314718055994530942f)

#if __has_builtin(__builtin_amdgcn_exp2f)
#define EXP2(x) __builtin_amdgcn_exp2f(x)
#else
#define EXP2(x) exp2f(x)
#endif
#if __has_builtin(__builtin_amdgcn_rcpf)
#define RCP(x) __builtin_amdgcn_rcpf(x)
#else
#define RCP(x) (1.0f / (x))
#endif

// LDS-only ordering within a wave (each wave touches only its own region;
// wave lockstep => lgkmcnt(0) is a sufficient producer-consumer barrier).
#define LDS_WAIT() asm volatile("s_waitcnt lgkmcnt(0)" ::: "memory")

typedef __attribute__((ext_vector_type(8))) __bf16 bf16x8;
typedef __attribute__((ext_vector_type(4))) float  f32x4;

// workspace float offsets
#define WS_C4   0      // 64 x float4 : {-log2e*W1[j][0], -log2e*W1[j][1], -log2e*b1[j], 0}
#define WS_G4   256    // 64 x float4 : -g_h[j]   (NLN2*LOG2E = -1 fold)
#define WS_D    512    // 4           : log2e * d_h
#define WS_ACC  768    // NSLOT x SLOTSTRIDE: [0..3]=l_h, [4+h*64+j]=T'_h[j]
#define NSLOT      16
#define SLOTSTRIDE 272

#define NPTS       (1024 * 1024)
#define K1_BLOCKS  2048
#define K1_THREADS 128
#define WAVES_TOTAL (K1_BLOCKS * 2)                   // 4096
#define GROUPS_PER_WAVE ((NPTS / 64) / WAVES_TOTAL)   // 4

// per-wave LDS region (shorts): p[16 rows x 72, rows 4+ alias into u] + u[64 x 72]
#define PW_SHORTS  288                     // 4 rows x 72 actually allocated
#define UW_SHORTS  (64 * 72)               // 4608
#define WAVE_SHORTS (PW_SHORTS + UW_SHORTS)  // 4896 (9792 B, mult of 16)

__device__ __forceinline__ unsigned short to_bf16(float x) {
    return (unsigned short)((__float_as_uint(x) + 0x8000u) >> 16);
}

// ---------------------------------------------------------------------------
// Setup: 64 blocks x 64 threads. Every block redundantly computes q and a
// (coalesced); block j computes g[j][h] lane-per-d + shuffle reduce. All
// blocks cooperatively zero the accumulator slots.
__global__ void setup_kernel(const float* __restrict__ W1, const float* __restrict__ b1,
                             const float* __restrict__ W2, const float* __restrict__ b2,
                             const float* __restrict__ query,
                             const float* __restrict__ ipw, const float* __restrict__ ipb,
                             float* __restrict__ ws)
{
    __shared__ float qv[64], qs[64], as4[4][64];
    const int t = threadIdx.x;
    const int b = blockIdx.x;     // = output j

    for (int i = b * 64 + t; i < NSLOT * SLOTSTRIDE; i += 64 * 64)
        ws[WS_ACC + i] = 0.0f;

    qv[t] = query[t];
    __syncthreads();

    {
        float a = ipb[t];
        #pragma unroll
        for (int k = 0; k < 64; ++k) a = fmaf(ipw[t * 64 + k], qv[k], a);
        qs[t] = a;
    }
    __syncthreads();

    #pragma unroll
    for (int h = 0; h < 4; ++h) {
        float a = 0.0f;
        #pragma unroll
        for (int m = 0; m < 16; ++m)
            a = fmaf(ipw[(64 + h * 16 + m) * 64 + t], qs[h * 16 + m], a);
        as4[h][t] = 0.25f * a;
    }
    __syncthreads();

    const float w2 = W2[t * 64 + b];
    float g[4];
    #pragma unroll
    for (int h = 0; h < 4; ++h) {
        float v = as4[h][t] * w2;
        for (int m = 1; m < 64; m <<= 1) v += __shfl_xor(v, m);
        g[h] = v;
    }
    if (t == 0) {
        ws[WS_G4 + b * 4 + 0] = -g[0];    // -g: LOG2E*NLN2 fold
        ws[WS_G4 + b * 4 + 1] = -g[1];
        ws[WS_G4 + b * 4 + 2] = -g[2];
        ws[WS_G4 + b * 4 + 3] = -g[3];
        ws[WS_C4 + b * 4 + 0] = -LOG2E * W1[2 * b];
        ws[WS_C4 + b * 4 + 1] = -LOG2E * W1[2 * b + 1];
        ws[WS_C4 + b * 4 + 2] = -LOG2E * b1[b];
        ws[WS_C4 + b * 4 + 3] = 0.0f;
    }
    if (b == 0 && t < 4) {
        float d = 0.0f;
        #pragma unroll
        for (int c = 0; c < 64; ++c) d += as4[t][c] * b2[c];
        float qb = 0.0f;
        #pragma unroll
        for (int m = 0; m < 16; ++m) qb += qs[t * 16 + m] * ipb[64 + t * 16 + m];
        ws[WS_D + t] = LOG2E * (d + 0.25f * qb);
    }
}

// ---------------------------------------------------------------------------
// Main: 2 independent waves/block (own LDS regions; pure-lgkm waits).
// Phase 1 (lane = point): ub_j = zn*rc, scores; stage bf16 ub -> [j][pt],
// bf16 p -> [h][pt]. Phase 2: 8x mfma_f32_16x16x32_bf16 per group:
//   D[j-tile(16) x h] += A(u)[m=j][k=pt] * B(p)[k=pt][n=h]
// A-frag: u[16tt+m][8q+i+32s]; B-frag: p[n][8q+i+32s] (rows n>=4 garbage,
// contaminates only D cols >=4 which are never read).
// D layout (verified): row = quad*4+reg = j_local, col = lane&15 = h.
__global__ __launch_bounds__(K1_THREADS) void main_kernel(
        const float* __restrict__ rr, const float* __restrict__ ri,
        const float4* __restrict__ c4g, const float4* __restrict__ g4g,
        const float* __restrict__ dvec, float* __restrict__ accb)
{
    __shared__ __align__(16) unsigned short lds[2][WAVE_SHORTS];

    const int t    = threadIdx.x;
    const int lane = t & 63;
    const int w    = t >> 6;
    const int m    = lane & 15;
    const int q    = lane >> 4;

    unsigned short* pw = lds[w];               // p: [h][pt], stride 72
    unsigned short* uw = lds[w] + PW_SHORTS;   // u: [j][pt], stride 72

    const float d0 = dvec[0], d1 = dvec[1], d2 = dvec[2], d3 = dvec[3];

    const int gwave = blockIdx.x * 2 + w;
    float l0 = 0, l1 = 0, l2 = 0, l3 = 0;
    f32x4 acc[4];
    #pragma unroll
    for (int i = 0; i < 4; ++i) acc[i] = (f32x4){0.f, 0.f, 0.f, 0.f};

    // hoist ALL global loads to kernel entry
    float rv[GROUPS_PER_WAVE], iv[GROUPS_PER_WAVE];
    #pragma unroll
    for (int it = 0; it < GROUPS_PER_WAVE; ++it) {
        const int idx = (gwave + it * WAVES_TOTAL) * 64 + lane;
        rv[it] = rr[idx];
        iv[it] = ri[idx];
    }

    for (int it = 0; it < GROUPS_PER_WAVE; ++it) {
        const float r  = rv[it];
        const float im = iv[it];

        float s0 = d0, s1 = d1, s2 = d2, s3 = d3;
        #pragma unroll 16
        for (int j = 0; j < 64; ++j) {
            const float4 c  = c4g[j];            // wave-uniform -> s_load
            const float4 gg = g4g[j];
            const float zn = fmaf(c.x, r, fmaf(c.y, im, c.z));   // -log2e * z
            const float e  = EXP2(zn);                           // exp(-z)
            const float rc = RCP(1.0f + e);                      // sigmoid(z)
            const float ub = zn * rc;            // = u / NLN2  (fold)
            s0 = fmaf(gg.x, ub, s0);
            s1 = fmaf(gg.y, ub, s1);
            s2 = fmaf(gg.z, ub, s2);
            s3 = fmaf(gg.w, ub, s3);
            uw[j * 72 + lane] = to_bf16(ub);
        }
        const float p0 = EXP2(s0), p1 = EXP2(s1), p2 = EXP2(s2), p3 = EXP2(s3);
        l0 += p0; l1 += p1; l2 += p2; l3 += p3;
        pw[0 * 72 + lane] = to_bf16(p0);
        pw[1 * 72 + lane] = to_bf16(p1);
        pw[2 * 72 + lane] = to_bf16(p2);
        pw[3 * 72 + lane] = to_bf16(p3);
        LDS_WAIT();    // writes visible to this wave's reads

        // B-frags (p), shared across j-tiles
        const bf16x8 b0 = *(const bf16x8*)(pw + m * 72 + q * 8);
        const bf16x8 b1 = *(const bf16x8*)(pw + m * 72 + q * 8 + 32);
        #pragma unroll
        for (int tt = 0; tt < 4; ++tt) {
            const bf16x8 a0 = *(const bf16x8*)(uw + (16 * tt + m) * 72 + q * 8);
            const bf16x8 a1 = *(const bf16x8*)(uw + (16 * tt + m) * 72 + q * 8 + 32);
            acc[tt] = __builtin_amdgcn_mfma_f32_16x16x32_bf16(a0, b0, acc[tt], 0, 0, 0);
            acc[tt] = __builtin_amdgcn_mfma_f32_16x16x32_bf16(a1, b1, acc[tt], 0, 0, 0);
        }
        LDS_WAIT();    // reads done before next iteration's writes (WAR)
    }

    // l: lane-local partials -> wave reduce
    for (int mm = 1; mm < 64; mm <<= 1) {
        l0 += __shfl_xor(l0, mm);
        l1 += __shfl_xor(l1, mm);
        l2 += __shfl_xor(l2, mm);
        l3 += __shfl_xor(l3, mm);
    }

    float* accS = accb + (blockIdx.x & (NSLOT - 1)) * SLOTSTRIDE;
    if (lane == 0) {
        atomicAdd(accS + 0, l0);
        atomicAdd(accS + 1, l1);
        atomicAdd(accS + 2, l2);
        atomicAdd(accS + 3, l3);
    }
    // D: row = q*4 + reg = j_local, col = m = h (cols 4..15 garbage -> skip)
    if (m < 4) {
        #pragma unroll
        for (int tt = 0; tt < 4; ++tt)
            #pragma unroll
            for (int reg = 0; reg < 4; ++reg)
                atomicAdd(accS + 4 + m * 64 + (16 * tt + 4 * q + reg), acc[tt][reg]);
    }
}

// ---------------------------------------------------------------------------
__global__ void finish_kernel(const float* __restrict__ W2, const float* __restrict__ b2,
                              const float* __restrict__ ipw, const float* __restrict__ ipb,
                              const float* __restrict__ opw, const float* __restrict__ opb,
                              const float* __restrict__ ws, float* __restrict__ out)
{
    __shared__ float red[260];   // [0..3]=l, [4+h*64+k]=T'
    __shared__ float sb[256];    // S-bar per (h, j)
    __shared__ float pl[64];     // pooled
    const int t = threadIdx.x;

    {
        float a = 0.0f;
        for (int s = 0; s < NSLOT; ++s) a += ws[WS_ACC + s * SLOTSTRIDE + t];
        red[t] = a;
        if (t < 4) {
            float a2 = 0.0f;
            for (int s = 0; s < NSLOT; ++s) a2 += ws[WS_ACC + s * SLOTSTRIDE + 256 + t];
            red[256 + t] = a2;
        }
    }
    __syncthreads();

    // S-bar_h[j] = W2[j][:] . (NLN2 * T'_h / l_h) + b2[j]
    {
        const int h = t >> 6, j = t & 63;
        const float inv = NLN2 / red[h];
        float a = 0.0f;
        #pragma unroll
        for (int k = 0; k < 64; ++k) a += W2[j * 64 + k] * red[4 + h * 64 + k];
        sb[t] = fmaf(inv, a, b2[j]);
    }
    __syncthreads();

    if (t < 64) {
        const int h = t >> 4;
        float a = ipb[128 + t];
        #pragma unroll
        for (int d = 0; d < 64; ++d) a += ipw[(128 + t) * 64 + d] * sb[h * 64 + d];
        pl[t] = a;
    }
    __syncthreads();

    if (t < 64) {
        float a = opb[t];
        #pragma unroll
        for (int p = 0; p < 64; ++p) a += opw[t * 64 + p] * pl[p];
        out[t] = a;
    }
}

// ---------------------------------------------------------------------------
extern "C" void kernel_launch(void* const* d_in, const int* in_sizes, int n_in,
                              void* d_out, int out_size, void* d_ws, size_t ws_size,
                              hipStream_t stream)
{
    const float* rr  = (const float*)d_in[0];   // rho_real
    const float* ri  = (const float*)d_in[1];   // rho_imag
    // d_in[2..5]: l_A, l_B, Z_A, Z_B — unused by the reference
    const float* W1  = (const float*)d_in[6];
    const float* b1  = (const float*)d_in[7];
    const float* W2  = (const float*)d_in[8];
    const float* b2  = (const float*)d_in[9];
    const float* qy  = (const float*)d_in[10];
    const float* ipw = (const float*)d_in[11];
    const float* ipb = (const float*)d_in[12];
    const float* opw = (const float*)d_in[13];
    const float* opb = (const float*)d_in[14];
    float* ws  = (float*)d_ws;
    float* out = (float*)d_out;

    setup_kernel<<<64, 64, 0, stream>>>(W1, b1, W2, b2, qy, ipw, ipb, ws);
    main_kernel<<<K1_BLOCKS, K1_THREADS, 0, stream>>>(
        rr, ri,
        (const float4*)(ws + WS_C4), (const float4*)(ws + WS_G4),
        ws + WS_D, ws + WS_ACC);
    finish_kernel<<<1, 256, 0, stream>>>(W2, b2, ipw, ipb, opw, opb, ws, out);
}

// Round 7
// 122.706 us; speedup vs baseline: 1.2867x; 1.2867x over previous
//
#include <hip/hip_runtime.h>

// ---------------------------------------------------------------------------
// UniversalBlockEncoder: algebraically folded attention pooling.
//
//   u_i = silu(W1 x_i + b1)                 (the only per-point nonlinearity)
//   s_h(i) = g_h . u_i + d_h    with g_h = W2^T (scale Wk_h^T q_h)
//   p = exp(s)  (scores O(3), f32-safe without max-subtraction)
//   T_h = sum_i p_h(i) u_i ,  l_h = sum_i p_h(i)
//   out = Wo ( Wv ( W2 (T/l) + b2 ) + bv ) + bo
//
// R7: R6 (MFMA phase-2) with the epilogue fixed: D-fragments transposed
//     through LDS so the global atomics are R5's proven coalesced full-wave
//     pattern (h*64+lane). R6's scattered 16-lane atomics caused 5x
//     WRITE_SIZE (25 MB) and the 44->70us regression.
// ---------------------------------------------------------------------------

#define LOG2E 1.44269504088896340736f
#define NLN2  (-0.69314718055994530942f)

#if __has_builtin(__builtin_amdgcn_exp2f)
#define EXP2(x) __builtin_amdgcn_exp2f(x)
#else
#define EXP2(x) exp2f(x)
#endif
#if __has_builtin(__builtin_amdgcn_rcpf)
#define RCP(x) __builtin_amdgcn_rcpf(x)
#else
#define RCP(x) (1.0f / (x))
#endif

// LDS-only ordering within a wave (each wave touches only its own region;
// wave lockstep => lgkmcnt(0) is a sufficient producer-consumer barrier).
#define LDS_WAIT() asm volatile("s_waitcnt lgkmcnt(0)" ::: "memory")

typedef __attribute__((ext_vector_type(8))) __bf16 bf16x8;
typedef __attribute__((ext_vector_type(4))) float  f32x4;

// workspace float offsets
#define WS_C4   0      // 64 x float4 : {-log2e*W1[j][0], -log2e*W1[j][1], -log2e*b1[j], 0}
#define WS_G4   256    // 64 x float4 : -g_h[j]   (NLN2*LOG2E = -1 fold)
#define WS_D    512    // 4           : log2e * d_h
#define WS_ACC  768    // NSLOT x SLOTSTRIDE: [0..3]=l_h, [4+h*64+j]=T'_h[j]
#define NSLOT      16
#define SLOTSTRIDE 272

#define NPTS       (1024 * 1024)
#define K1_BLOCKS  2048
#define K1_THREADS 128
#define WAVES_TOTAL (K1_BLOCKS * 2)                   // 4096
#define GROUPS_PER_WAVE ((NPTS / 64) / WAVES_TOTAL)   // 4

// per-wave LDS region (shorts): p[4 x 72] + u[64 x 72]
#define PW_SHORTS  288
#define UW_SHORTS  (64 * 72)
#define WAVE_SHORTS (PW_SHORTS + UW_SHORTS)  // 4896 shorts (9792 B)

__device__ __forceinline__ unsigned short to_bf16(float x) {
    return (unsigned short)((__float_as_uint(x) + 0x8000u) >> 16);
}

// ---------------------------------------------------------------------------
// Setup: 64 blocks x 64 threads. Every block redundantly computes q and a
// (coalesced); block j computes g[j][h] lane-per-d + shuffle reduce. All
// blocks cooperatively zero the accumulator slots.
__global__ void setup_kernel(const float* __restrict__ W1, const float* __restrict__ b1,
                             const float* __restrict__ W2, const float* __restrict__ b2,
                             const float* __restrict__ query,
                             const float* __restrict__ ipw, const float* __restrict__ ipb,
                             float* __restrict__ ws)
{
    __shared__ float qv[64], qs[64], as4[4][64];
    const int t = threadIdx.x;
    const int b = blockIdx.x;     // = output j

    for (int i = b * 64 + t; i < NSLOT * SLOTSTRIDE; i += 64 * 64)
        ws[WS_ACC + i] = 0.0f;

    qv[t] = query[t];
    __syncthreads();

    {
        float a = ipb[t];
        #pragma unroll
        for (int k = 0; k < 64; ++k) a = fmaf(ipw[t * 64 + k], qv[k], a);
        qs[t] = a;
    }
    __syncthreads();

    #pragma unroll
    for (int h = 0; h < 4; ++h) {
        float a = 0.0f;
        #pragma unroll
        for (int m = 0; m < 16; ++m)
            a = fmaf(ipw[(64 + h * 16 + m) * 64 + t], qs[h * 16 + m], a);
        as4[h][t] = 0.25f * a;
    }
    __syncthreads();

    const float w2 = W2[t * 64 + b];
    float g[4];
    #pragma unroll
    for (int h = 0; h < 4; ++h) {
        float v = as4[h][t] * w2;
        for (int m = 1; m < 64; m <<= 1) v += __shfl_xor(v, m);
        g[h] = v;
    }
    if (t == 0) {
        ws[WS_G4 + b * 4 + 0] = -g[0];    // -g: LOG2E*NLN2 fold
        ws[WS_G4 + b * 4 + 1] = -g[1];
        ws[WS_G4 + b * 4 + 2] = -g[2];
        ws[WS_G4 + b * 4 + 3] = -g[3];
        ws[WS_C4 + b * 4 + 0] = -LOG2E * W1[2 * b];
        ws[WS_C4 + b * 4 + 1] = -LOG2E * W1[2 * b + 1];
        ws[WS_C4 + b * 4 + 2] = -LOG2E * b1[b];
        ws[WS_C4 + b * 4 + 3] = 0.0f;
    }
    if (b == 0 && t < 4) {
        float d = 0.0f;
        #pragma unroll
        for (int c = 0; c < 64; ++c) d += as4[t][c] * b2[c];
        float qb = 0.0f;
        #pragma unroll
        for (int m = 0; m < 16; ++m) qb += qs[t * 16 + m] * ipb[64 + t * 16 + m];
        ws[WS_D + t] = LOG2E * (d + 0.25f * qb);
    }
}

// ---------------------------------------------------------------------------
// Main: 2 independent waves/block (own LDS regions; pure-lgkm waits).
// Phase 1 (lane = point): ub_j = zn*rc, scores; stage bf16 ub -> [j][pt],
// bf16 p -> [h][pt]. Phase 2: 8x mfma_f32_16x16x32_bf16 per group:
//   D[j-tile(16) x h] += A(u)[m=j][k=pt] * B(p)[k=pt][n=h]
// (B rows n>=4 garbage -> contaminates only D cols >=4, never read.)
// Epilogue: transpose D via LDS so atomics are coalesced full-wave.
__global__ __launch_bounds__(K1_THREADS) void main_kernel(
        const float* __restrict__ rr, const float* __restrict__ ri,
        const float4* __restrict__ c4g, const float4* __restrict__ g4g,
        const float* __restrict__ dvec, float* __restrict__ accb)
{
    __shared__ __align__(16) unsigned short lds[2][WAVE_SHORTS];

    const int t    = threadIdx.x;
    const int lane = t & 63;
    const int w    = t >> 6;
    const int m    = lane & 15;
    const int q    = lane >> 4;

    unsigned short* pw = lds[w];               // p: [h][pt], stride 72
    unsigned short* uw = lds[w] + PW_SHORTS;   // u: [j][pt], stride 72

    const float d0 = dvec[0], d1 = dvec[1], d2 = dvec[2], d3 = dvec[3];

    const int gwave = blockIdx.x * 2 + w;
    float l0 = 0, l1 = 0, l2 = 0, l3 = 0;
    f32x4 acc[4];
    #pragma unroll
    for (int i = 0; i < 4; ++i) acc[i] = (f32x4){0.f, 0.f, 0.f, 0.f};

    // hoist ALL global loads to kernel entry
    float rv[GROUPS_PER_WAVE], iv[GROUPS_PER_WAVE];
    #pragma unroll
    for (int it = 0; it < GROUPS_PER_WAVE; ++it) {
        const int idx = (gwave + it * WAVES_TOTAL) * 64 + lane;
        rv[it] = rr[idx];
        iv[it] = ri[idx];
    }

    for (int it = 0; it < GROUPS_PER_WAVE; ++it) {
        const float r  = rv[it];
        const float im = iv[it];

        float s0 = d0, s1 = d1, s2 = d2, s3 = d3;
        #pragma unroll 16
        for (int j = 0; j < 64; ++j) {
            const float4 c  = c4g[j];            // wave-uniform -> s_load
            const float4 gg = g4g[j];
            const float zn = fmaf(c.x, r, fmaf(c.y, im, c.z));   // -log2e * z
            const float e  = EXP2(zn);                           // exp(-z)
            const float rc = RCP(1.0f + e);                      // sigmoid(z)
            const float ub = zn * rc;            // = u / NLN2  (fold)
            s0 = fmaf(gg.x, ub, s0);
            s1 = fmaf(gg.y, ub, s1);
            s2 = fmaf(gg.z, ub, s2);
            s3 = fmaf(gg.w, ub, s3);
            uw[j * 72 + lane] = to_bf16(ub);
        }
        const float p0 = EXP2(s0), p1 = EXP2(s1), p2 = EXP2(s2), p3 = EXP2(s3);
        l0 += p0; l1 += p1; l2 += p2; l3 += p3;
        pw[0 * 72 + lane] = to_bf16(p0);
        pw[1 * 72 + lane] = to_bf16(p1);
        pw[2 * 72 + lane] = to_bf16(p2);
        pw[3 * 72 + lane] = to_bf16(p3);
        LDS_WAIT();    // writes visible to this wave's reads

        // B-frags (p), shared across j-tiles
        const bf16x8 b0 = *(const bf16x8*)(pw + m * 72 + q * 8);
        const bf16x8 b1 = *(const bf16x8*)(pw + m * 72 + q * 8 + 32);
        #pragma unroll
        for (int tt = 0; tt < 4; ++tt) {
            const bf16x8 a0 = *(const bf16x8*)(uw + (16 * tt + m) * 72 + q * 8);
            const bf16x8 a1 = *(const bf16x8*)(uw + (16 * tt + m) * 72 + q * 8 + 32);
            acc[tt] = __builtin_amdgcn_mfma_f32_16x16x32_bf16(a0, b0, acc[tt], 0, 0, 0);
            acc[tt] = __builtin_amdgcn_mfma_f32_16x16x32_bf16(a1, b1, acc[tt], 0, 0, 0);
        }
        LDS_WAIT();    // reads done before next iteration's writes (WAR)
    }

    // l: lane-local partials -> wave reduce
    for (int mm = 1; mm < 64; mm <<= 1) {
        l0 += __shfl_xor(l0, mm);
        l1 += __shfl_xor(l1, mm);
        l2 += __shfl_xor(l2, mm);
        l3 += __shfl_xor(l3, mm);
    }

    // ---- epilogue: transpose D via LDS -> coalesced atomics ----
    // D: row = q*4 + reg = j_local(16tt..), col = m = h (cols 4..15 garbage)
    // scr[h][j], stride 66: writes <=2-way banks, reads 2-way (both free).
    float* scr = (float*)uw;   // reuse u region (>= 264 floats available)
    if (m < 4) {
        #pragma unroll
        for (int tt = 0; tt < 4; ++tt)
            #pragma unroll
            for (int reg = 0; reg < 4; ++reg)
                scr[m * 66 + 16 * tt + 4 * q + reg] = acc[tt][reg];
    }
    LDS_WAIT();
    float Th[4];
    #pragma unroll
    for (int h = 0; h < 4; ++h) Th[h] = scr[h * 66 + lane];

    float* accS = accb + (blockIdx.x & (NSLOT - 1)) * SLOTSTRIDE;
    if (lane == 0) {
        atomicAdd(accS + 0, l0);
        atomicAdd(accS + 1, l1);
        atomicAdd(accS + 2, l2);
        atomicAdd(accS + 3, l3);
    }
    atomicAdd(accS + 4 + 0 * 64 + lane, Th[0]);
    atomicAdd(accS + 4 + 1 * 64 + lane, Th[1]);
    atomicAdd(accS + 4 + 2 * 64 + lane, Th[2]);
    atomicAdd(accS + 4 + 3 * 64 + lane, Th[3]);
}

// ---------------------------------------------------------------------------
__global__ void finish_kernel(const float* __restrict__ W2, const float* __restrict__ b2,
                              const float* __restrict__ ipw, const float* __restrict__ ipb,
                              const float* __restrict__ opw, const float* __restrict__ opb,
                              const float* __restrict__ ws, float* __restrict__ out)
{
    __shared__ float red[260];   // [0..3]=l, [4+h*64+k]=T'
    __shared__ float sb[256];    // S-bar per (h, j)
    __shared__ float pl[64];     // pooled
    const int t = threadIdx.x;

    {
        float a = 0.0f;
        for (int s = 0; s < NSLOT; ++s) a += ws[WS_ACC + s * SLOTSTRIDE + t];
        red[t] = a;
        if (t < 4) {
            float a2 = 0.0f;
            for (int s = 0; s < NSLOT; ++s) a2 += ws[WS_ACC + s * SLOTSTRIDE + 256 + t];
            red[256 + t] = a2;
        }
    }
    __syncthreads();

    // S-bar_h[j] = W2[j][:] . (NLN2 * T'_h / l_h) + b2[j]
    {
        const int h = t >> 6, j = t & 63;
        const float inv = NLN2 / red[h];
        float a = 0.0f;
        #pragma unroll
        for (int k = 0; k < 64; ++k) a += W2[j * 64 + k] * red[4 + h * 64 + k];
        sb[t] = fmaf(inv, a, b2[j]);
    }
    __syncthreads();

    if (t < 64) {
        const int h = t >> 4;
        float a = ipb[128 + t];
        #pragma unroll
        for (int d = 0; d < 64; ++d) a += ipw[(128 + t) * 64 + d] * sb[h * 64 + d];
        pl[t] = a;
    }
    __syncthreads();

    if (t < 64) {
        float a = opb[t];
        #pragma unroll
        for (int p = 0; p < 64; ++p) a += opw[t * 64 + p] * pl[p];
        out[t] = a;
    }
}

// ---------------------------------------------------------------------------
extern "C" void kernel_launch(void* const* d_in, const int* in_sizes, int n_in,
                              void* d_out, int out_size, void* d_ws, size_t ws_size,
                              hipStream_t stream)
{
    const float* rr  = (const float*)d_in[0];   // rho_real
    const float* ri  = (const float*)d_in[1];   // rho_imag
    // d_in[2..5]: l_A, l_B, Z_A, Z_B — unused by the reference
    const float* W1  = (const float*)d_in[6];
    const float* b1  = (const float*)d_in[7];
    const float* W2  = (const float*)d_in[8];
    const float* b2  = (const float*)d_in[9];
    const float* qy  = (const float*)d_in[10];
    const float* ipw = (const float*)d_in[11];
    const float* ipb = (const float*)d_in[12];
    const float* opw = (const float*)d_in[13];
    const float* opb = (const float*)d_in[14];
    float* ws  = (float*)d_ws;
    float* out = (float*)d_out;

    setup_kernel<<<64, 64, 0, stream>>>(W1, b1, W2, b2, qy, ipw, ipb, ws);
    main_kernel<<<K1_BLOCKS, K1_THREADS, 0, stream>>>(
        rr, ri,
        (const float4*)(ws + WS_C4), (const float4*)(ws + WS_G4),
        ws + WS_D, ws + WS_ACC);
    finish_kernel<<<1, 256, 0, stream>>>(W2, b2, ipw, ipb, opw, opb, ws, out);
}